// Round 1
// baseline (277.349 us; speedup 1.0000x reference)
//
#include <hip/hip_runtime.h>
#include <cmath>

#define B_    4
#define S_    512
#define NH_   8
#define KS_   32
#define KR_   8
#define VS_   32
#define HID_  256
#define RS_   16
#define TOT_  104      // 2*KS + VS + KR
#define NQKV_ 832      // NH*TOT
#define ROWS_ 2048     // B*S

// ---------------------------------------------------------------------------
// K1: H2[row, h*104+c] = H[row,:] @ W_qkv[c,:]   (2048 x 832 x 256)
// ---------------------------------------------------------------------------
__global__ __launch_bounds__(256) void k1_qkv(const float* __restrict__ Hin,
                                              const float* __restrict__ Wqkv,
                                              float* __restrict__ H2) {
  __shared__ float As[64][33];
  __shared__ float Bs[64][33];
  const int t = threadIdx.x;
  const int tx = t & 15, ty = t >> 4;
  const int i0 = blockIdx.y * 64, j0 = blockIdx.x * 64;
  const int lr = t >> 2, lc = (t & 3) * 8;
  float acc[4][4] = {};
  for (int k0 = 0; k0 < HID_; k0 += 32) {
    float4 a0 = *(const float4*)(Hin + (size_t)(i0 + lr) * HID_ + k0 + lc);
    float4 a1 = *(const float4*)(Hin + (size_t)(i0 + lr) * HID_ + k0 + lc + 4);
    float4 b0 = *(const float4*)(Wqkv + (size_t)(j0 + lr) * HID_ + k0 + lc);
    float4 b1 = *(const float4*)(Wqkv + (size_t)(j0 + lr) * HID_ + k0 + lc + 4);
    __syncthreads();
    As[lr][lc+0]=a0.x; As[lr][lc+1]=a0.y; As[lr][lc+2]=a0.z; As[lr][lc+3]=a0.w;
    As[lr][lc+4]=a1.x; As[lr][lc+5]=a1.y; As[lr][lc+6]=a1.z; As[lr][lc+7]=a1.w;
    Bs[lr][lc+0]=b0.x; Bs[lr][lc+1]=b0.y; Bs[lr][lc+2]=b0.z; Bs[lr][lc+3]=b0.w;
    Bs[lr][lc+4]=b1.x; Bs[lr][lc+5]=b1.y; Bs[lr][lc+6]=b1.z; Bs[lr][lc+7]=b1.w;
    __syncthreads();
#pragma unroll
    for (int k = 0; k < 32; ++k) {
      float a[4], bb[4];
#pragma unroll
      for (int r = 0; r < 4; ++r) a[r] = As[ty*4+r][k];
#pragma unroll
      for (int c = 0; c < 4; ++c) bb[c] = Bs[tx*4+c][k];
#pragma unroll
      for (int r = 0; r < 4; ++r)
#pragma unroll
        for (int c = 0; c < 4; ++c) acc[r][c] += a[r]*bb[c];
    }
  }
#pragma unroll
  for (int r = 0; r < 4; ++r) {
    float4 v = make_float4(acc[r][0], acc[r][1], acc[r][2], acc[r][3]);
    *(float4*)(H2 + (size_t)(i0 + ty*4 + r) * NQKV_ + j0 + tx*4) = v;
  }
}

// ---------------------------------------------------------------------------
// K2: qk[b,h,i,j] = Qn[b,h,i,:] . Kn[b,h,j,:]   (batched 512x512x32)
// ---------------------------------------------------------------------------
__global__ __launch_bounds__(256) void k2_qk(const float* __restrict__ H2,
                                             float* __restrict__ qk) {
  __shared__ float As[64][33];
  __shared__ float Bs[64][33];
  const int t = threadIdx.x;
  const int tx = t & 15, ty = t >> 4;
  const int bz = blockIdx.z;            // b*8 + h
  const int b = bz >> 3, h = bz & 7;
  const int i0 = blockIdx.y * 64, j0 = blockIdx.x * 64;
  const float* Abase = H2 + (size_t)b * S_ * NQKV_ + h * TOT_;        // Qn
  const float* Bbase = H2 + (size_t)b * S_ * NQKV_ + h * TOT_ + KS_;  // Kn
  const int lr = t >> 2, lc = (t & 3) * 8;

  float4 a0 = *(const float4*)(Abase + (size_t)(i0 + lr) * NQKV_ + lc);
  float4 a1 = *(const float4*)(Abase + (size_t)(i0 + lr) * NQKV_ + lc + 4);
  float4 b0 = *(const float4*)(Bbase + (size_t)(j0 + lr) * NQKV_ + lc);
  float4 b1 = *(const float4*)(Bbase + (size_t)(j0 + lr) * NQKV_ + lc + 4);
  As[lr][lc+0]=a0.x; As[lr][lc+1]=a0.y; As[lr][lc+2]=a0.z; As[lr][lc+3]=a0.w;
  As[lr][lc+4]=a1.x; As[lr][lc+5]=a1.y; As[lr][lc+6]=a1.z; As[lr][lc+7]=a1.w;
  Bs[lr][lc+0]=b0.x; Bs[lr][lc+1]=b0.y; Bs[lr][lc+2]=b0.z; Bs[lr][lc+3]=b0.w;
  Bs[lr][lc+4]=b1.x; Bs[lr][lc+5]=b1.y; Bs[lr][lc+6]=b1.z; Bs[lr][lc+7]=b1.w;
  __syncthreads();

  float acc[4][4] = {};
#pragma unroll
  for (int k = 0; k < 32; ++k) {
    float a[4], bb[4];
#pragma unroll
    for (int r = 0; r < 4; ++r) a[r] = As[ty*4+r][k];
#pragma unroll
    for (int c = 0; c < 4; ++c) bb[c] = Bs[tx*4+c][k];
#pragma unroll
    for (int r = 0; r < 4; ++r)
#pragma unroll
      for (int c = 0; c < 4; ++c) acc[r][c] += a[r]*bb[c];
  }
#pragma unroll
  for (int r = 0; r < 4; ++r) {
    float4 v = make_float4(acc[r][0], acc[r][1], acc[r][2], acc[r][3]);
    *(float4*)(qk + (((size_t)bz * S_ + i0 + ty*4 + r) * S_) + j0 + tx*4) = v;
  }
}

// ---------------------------------------------------------------------------
// K3: per (b,i): scores = scale*(qk + qrr.rd) + mask ; softmax ;
//     probs -> qk (in place) ; pr = p.rd ; ctx_route = pr @ Wroute_h.T
// ---------------------------------------------------------------------------
__global__ __launch_bounds__(256) void k3_route(const float* __restrict__ rd,
                                                const float* __restrict__ H2,
                                                const float* __restrict__ Wd,
                                                const float* __restrict__ Wroute,
                                                const float* __restrict__ mask,
                                                float* __restrict__ qk,
                                                float* __restrict__ ctx) {
  __shared__ float rdr[512][17];
  __shared__ float sc[8][512];
  __shared__ float qrr[8][16];
  __shared__ float prp[2][8][16];
  __shared__ float prf[8][16];
  const int t = threadIdx.x;
  const int row = blockIdx.x;        // b*512 + i
  const int b = row >> 9;
  const int i = row & 511;

  // 1. stage route_data row (512 x 16 f32)
  const float4* rp = (const float4*)(rd + (size_t)row * 512 * 16);
#pragma unroll
  for (int q = 0; q < 8; ++q) {
    int idx = q * 256 + t;
    float4 v = rp[idx];
    int j = idx >> 2, c0 = (idx & 3) * 4;
    rdr[j][c0+0] = v.x; rdr[j][c0+1] = v.y; rdr[j][c0+2] = v.z; rdr[j][c0+3] = v.w;
  }
  // 2. qrr[h][r] = sum_k Qr[h][k] * Wd[h*8+k][r]
  if (t < 128) {
    int h = t >> 4, r = t & 15;
    float s = 0.f;
#pragma unroll
    for (int k = 0; k < 8; ++k)
      s += H2[(size_t)row * NQKV_ + h * TOT_ + 96 + k] * Wd[(h*8 + k) * 16 + r];
    qrr[h][r] = s;
  }
  __syncthreads();

  // 3. scores
  const float scal = 0.15811388300841898f;   // 1/sqrt(40)
#pragma unroll
  for (int rep = 0; rep < 16; ++rep) {
    int idx = rep * 256 + t;
    int h = idx >> 9, j = idx & 511;
    float qv = qk[(((size_t)b*8 + h) * S_ + i) * S_ + j];
    float s2 = 0.f;
#pragma unroll
    for (int r = 0; r < 16; ++r) s2 += qrr[h][r] * rdr[j][r];
    sc[h][j] = scal * (qv + s2) + mask[b * S_ + j];
  }
  __syncthreads();

  // 4. softmax per head (one wave handles 2 heads), write probs in place
  const int wave = t >> 6, lane = t & 63;
  for (int hh = 0; hh < 2; ++hh) {
    int h = wave * 2 + hh;
    float vals[8];
    float m = -1e30f;
#pragma unroll
    for (int c = 0; c < 8; ++c) { vals[c] = sc[h][lane + 64*c]; m = fmaxf(m, vals[c]); }
#pragma unroll
    for (int o = 32; o; o >>= 1) m = fmaxf(m, __shfl_xor(m, o));
    float ssum = 0.f;
#pragma unroll
    for (int c = 0; c < 8; ++c) { vals[c] = __expf(vals[c] - m); ssum += vals[c]; }
#pragma unroll
    for (int o = 32; o; o >>= 1) ssum += __shfl_xor(ssum, o);
    float inv = 1.0f / ssum;
#pragma unroll
    for (int c = 0; c < 8; ++c) {
      int j = lane + 64*c;
      float p = vals[c] * inv;
      sc[h][j] = p;
      qk[(((size_t)b*8 + h) * S_ + i) * S_ + j] = p;
    }
  }
  __syncthreads();

  // 5. pr[h][r] = sum_j p[h][j] * rd[j][r]   (split over two j-halves)
  {
    int pair = t & 127, half = t >> 7;
    int h = pair >> 4, r = pair & 15;
    float s = 0.f;
    int j0 = half * 256;
    for (int j = j0; j < j0 + 256; ++j) s += sc[h][j] * rdr[j][r];
    prp[half][h][r] = s;
  }
  __syncthreads();
  if (t < 128) {
    int h = t >> 4, r = t & 15;
    prf[h][r] = prp[0][h][r] + prp[1][h][r];
  }
  __syncthreads();

  // 6. route context: ctx[row, h*32+v] = sum_r prf[h][r]*Wroute[(h*32+v)*16+r]
  {
    int h = t >> 5;
    float s = 0.f;
#pragma unroll
    for (int r = 0; r < 16; ++r) s += prf[h][r] * Wroute[t * 16 + r];
    ctx[(size_t)row * 256 + t] = s;
  }
}

// ---------------------------------------------------------------------------
// K4: ctx[b, i, h*32+v] += sum_j probs[b,h,i,j] * V[b,h,j,v]
// ---------------------------------------------------------------------------
__global__ __launch_bounds__(256) void k4_pv(const float* __restrict__ probs,
                                             const float* __restrict__ H2,
                                             float* __restrict__ ctx) {
  __shared__ float Pt[64][65];
  __shared__ float Vt[64][33];
  const int t = threadIdx.x;
  const int bz = blockIdx.y;           // b*8+h
  const int b = bz >> 3, h = bz & 7;
  const int i0 = blockIdx.x * 64;
  const int v = t & 31, ig = t >> 5;   // ig in 0..7
  const float* Pbase = probs + ((size_t)bz * S_ + i0) * S_;
  const float* Vbase = H2 + (size_t)b * S_ * NQKV_ + h * TOT_ + 2*KS_;
  const int pr_ = t >> 2, pc = (t & 3) * 16;
  const int vr = t >> 2, vc = (t & 3) * 8;
  float acc[8] = {};

  for (int jt = 0; jt < 8; ++jt) {
    float4 p0 = *(const float4*)(Pbase + (size_t)pr_ * S_ + jt*64 + pc);
    float4 p1 = *(const float4*)(Pbase + (size_t)pr_ * S_ + jt*64 + pc + 4);
    float4 p2 = *(const float4*)(Pbase + (size_t)pr_ * S_ + jt*64 + pc + 8);
    float4 p3 = *(const float4*)(Pbase + (size_t)pr_ * S_ + jt*64 + pc + 12);
    float4 v0 = *(const float4*)(Vbase + (size_t)(jt*64 + vr) * NQKV_ + vc);
    float4 v1 = *(const float4*)(Vbase + (size_t)(jt*64 + vr) * NQKV_ + vc + 4);
    __syncthreads();
    Pt[pr_][pc+0]=p0.x;  Pt[pr_][pc+1]=p0.y;  Pt[pr_][pc+2]=p0.z;  Pt[pr_][pc+3]=p0.w;
    Pt[pr_][pc+4]=p1.x;  Pt[pr_][pc+5]=p1.y;  Pt[pr_][pc+6]=p1.z;  Pt[pr_][pc+7]=p1.w;
    Pt[pr_][pc+8]=p2.x;  Pt[pr_][pc+9]=p2.y;  Pt[pr_][pc+10]=p2.z; Pt[pr_][pc+11]=p2.w;
    Pt[pr_][pc+12]=p3.x; Pt[pr_][pc+13]=p3.y; Pt[pr_][pc+14]=p3.z; Pt[pr_][pc+15]=p3.w;
    Vt[vr][vc+0]=v0.x; Vt[vr][vc+1]=v0.y; Vt[vr][vc+2]=v0.z; Vt[vr][vc+3]=v0.w;
    Vt[vr][vc+4]=v1.x; Vt[vr][vc+5]=v1.y; Vt[vr][vc+6]=v1.z; Vt[vr][vc+7]=v1.w;
    __syncthreads();
#pragma unroll
    for (int j = 0; j < 64; ++j) {
      float vv = Vt[j][v];
#pragma unroll
      for (int r = 0; r < 8; ++r) acc[r] += Pt[r*8 + ig][j] * vv;
    }
  }
#pragma unroll
  for (int r = 0; r < 8; ++r) {
    size_t addr = ((size_t)b * S_ + i0 + r*8 + ig) * 256 + h*32 + v;
    ctx[addr] += acc[r];
  }
}

// ---------------------------------------------------------------------------
// K5: out = LN(ctx @ W_out.T + b_out) + H     (16 rows per block)
// ---------------------------------------------------------------------------
__global__ __launch_bounds__(256) void k5_out(const float* __restrict__ ctx,
                                              const float* __restrict__ Wout,
                                              const float* __restrict__ bout,
                                              const float* __restrict__ lnw,
                                              const float* __restrict__ lnb,
                                              const float* __restrict__ Hin,
                                              float* __restrict__ out) {
  __shared__ float buf[16][257];
  __shared__ float uarr[16], rarr[16];
  const int t = threadIdx.x;
  const int R0 = blockIdx.x * 16;
  // stage 16 ctx rows
  {
    int sr = t >> 4, c0 = (t & 15) * 16;
    const float4* cp = (const float4*)(ctx + (size_t)(R0 + sr) * 256 + c0);
    float4 a = cp[0], b = cp[1], c = cp[2], d = cp[3];
    buf[sr][c0+0]=a.x;  buf[sr][c0+1]=a.y;  buf[sr][c0+2]=a.z;  buf[sr][c0+3]=a.w;
    buf[sr][c0+4]=b.x;  buf[sr][c0+5]=b.y;  buf[sr][c0+6]=b.z;  buf[sr][c0+7]=b.w;
    buf[sr][c0+8]=c.x;  buf[sr][c0+9]=c.y;  buf[sr][c0+10]=c.z; buf[sr][c0+11]=c.w;
    buf[sr][c0+12]=d.x; buf[sr][c0+13]=d.y; buf[sr][c0+14]=d.z; buf[sr][c0+15]=d.w;
  }
  __syncthreads();

  float o[16];
  {
    float bo = bout[t];
#pragma unroll
    for (int r = 0; r < 16; ++r) o[r] = bo;
  }
  const float4* wp = (const float4*)(Wout + (size_t)t * 256);
  for (int d4 = 0; d4 < 64; ++d4) {
    float4 w = wp[d4];
    int d = d4 * 4;
#pragma unroll
    for (int r = 0; r < 16; ++r)
      o[r] += buf[r][d]*w.x + buf[r][d+1]*w.y + buf[r][d+2]*w.z + buf[r][d+3]*w.w;
  }
  __syncthreads();
  // write o back to buf for cross-thread LN reduction
#pragma unroll
  for (int r = 0; r < 16; ++r) buf[r][t] = o[r];
  __syncthreads();
  {
    int wave = t >> 6, lane = t & 63;
    for (int rr = 0; rr < 4; ++rr) {
      int r = wave * 4 + rr;
      float s = 0.f, sq = 0.f;
#pragma unroll
      for (int c = 0; c < 4; ++c) {
        float x = buf[r][lane + 64*c];
        s += x; sq += x*x;
      }
#pragma unroll
      for (int off = 32; off; off >>= 1) {
        s += __shfl_xor(s, off);
        sq += __shfl_xor(sq, off);
      }
      if (lane == 0) {
        float u = s * (1.0f/256.0f);
        uarr[r] = u;
        rarr[r] = rsqrtf(sq * (1.0f/256.0f) - u*u + 1e-12f);
      }
    }
  }
  __syncthreads();
  {
    float lw = lnw[t], lb = lnb[t];
#pragma unroll
    for (int r = 0; r < 16; ++r) {
      size_t R = R0 + r;
      out[R * 256 + t] = lw * (o[r] - uarr[r]) * rarr[r] + lb + Hin[R * 256 + t];
    }
  }
}

// ---------------------------------------------------------------------------
extern "C" void kernel_launch(void* const* d_in, const int* in_sizes, int n_in,
                              void* d_out, int out_size, void* d_ws, size_t ws_size,
                              hipStream_t stream) {
  const float* Hin    = (const float*)d_in[0];
  const float* rd     = (const float*)d_in[1];
  const float* mask   = (const float*)d_in[2];
  const float* Wqkv   = (const float*)d_in[3];
  const float* Wd     = (const float*)d_in[4];
  const float* Wroute = (const float*)d_in[5];
  const float* Wout   = (const float*)d_in[6];
  const float* bout   = (const float*)d_in[7];
  const float* lnw    = (const float*)d_in[8];
  const float* lnb    = (const float*)d_in[9];
  float* out = (float*)d_out;

  float* H2  = (float*)d_ws;                           // 2048*832   = 1,703,936 f
  float* qk  = H2 + (size_t)ROWS_ * NQKV_;             // 32*512*512 = 8,388,608 f (scores -> probs in place)
  float* ctx = qk + (size_t)B_ * NH_ * S_ * S_;        // 2048*256   =   524,288 f

  k1_qkv <<<dim3(13, 32),   256, 0, stream>>>(Hin, Wqkv, H2);
  k2_qk  <<<dim3(8, 8, 32), 256, 0, stream>>>(H2, qk);
  k3_route<<<dim3(2048),    256, 0, stream>>>(rd, H2, Wd, Wroute, mask, qk, ctx);
  k4_pv  <<<dim3(8, 32),    256, 0, stream>>>(qk, H2, ctx);
  k5_out <<<dim3(128),      256, 0, stream>>>(ctx, Wout, bout, lnw, lnb, Hin, out);
}

// Round 2
// 263.875 us; speedup vs baseline: 1.0511x; 1.0511x over previous
//
#include <hip/hip_runtime.h>
#include <cmath>

#define B_    4
#define S_    512
#define NH_   8
#define KS_   32
#define KR_   8
#define VS_   32
#define HID_  256
#define RS_   16
#define TOT_  104      // 2*KS + VS + KR
#define NQKV_ 832      // NH*TOT
#define ROWS_ 2048     // B*S

// bf16 (as ushort) -> f32
__device__ inline float bfu2f(unsigned int bits16) {
  union { unsigned int i; float f; } v; v.i = bits16 << 16; return v.f;
}
// f32 -> bf16 bits (RNE)
__device__ inline unsigned short f2bf(float f) {
  union { float f; unsigned int i; } v; v.f = f;
  unsigned int r = v.i + 0x7fffu + ((v.i >> 16) & 1u);
  return (unsigned short)(r >> 16);
}
// dot of 8 f32 (regs) with 8 bf16 packed in a uint4
__device__ inline float qk8(const float* qf, uint4 u) {
  return qf[0]*bfu2f(u.x & 0xffffu) + qf[1]*bfu2f(u.x >> 16)
       + qf[2]*bfu2f(u.y & 0xffffu) + qf[3]*bfu2f(u.y >> 16)
       + qf[4]*bfu2f(u.z & 0xffffu) + qf[5]*bfu2f(u.z >> 16)
       + qf[6]*bfu2f(u.w & 0xffffu) + qf[7]*bfu2f(u.w >> 16);
}

// ---------------------------------------------------------------------------
// K1: H2[row, h*104+c] = H[row,:] @ W_qkv[c,:]   (2048 x 832 x 256)
// Transposed LDS (As[k][row]) so fragment reads are ds_read_b128.
// ---------------------------------------------------------------------------
__global__ __launch_bounds__(256) void k1_qkv(const float* __restrict__ Hin,
                                              const float* __restrict__ Wqkv,
                                              float* __restrict__ H2) {
  __shared__ float As[32][68];
  __shared__ float Bs[32][68];
  const int t = threadIdx.x;
  const int tx = t & 15, ty = t >> 4;
  const int i0 = blockIdx.y * 64, j0 = blockIdx.x * 64;
  const int lr = t >> 2, lc = (t & 3) * 8;
  float acc[4][4] = {};
  for (int k0 = 0; k0 < HID_; k0 += 32) {
    float4 a0 = *(const float4*)(Hin + (size_t)(i0 + lr) * HID_ + k0 + lc);
    float4 a1 = *(const float4*)(Hin + (size_t)(i0 + lr) * HID_ + k0 + lc + 4);
    float4 b0 = *(const float4*)(Wqkv + (size_t)(j0 + lr) * HID_ + k0 + lc);
    float4 b1 = *(const float4*)(Wqkv + (size_t)(j0 + lr) * HID_ + k0 + lc + 4);
    __syncthreads();
    As[lc+0][lr]=a0.x; As[lc+1][lr]=a0.y; As[lc+2][lr]=a0.z; As[lc+3][lr]=a0.w;
    As[lc+4][lr]=a1.x; As[lc+5][lr]=a1.y; As[lc+6][lr]=a1.z; As[lc+7][lr]=a1.w;
    Bs[lc+0][lr]=b0.x; Bs[lc+1][lr]=b0.y; Bs[lc+2][lr]=b0.z; Bs[lc+3][lr]=b0.w;
    Bs[lc+4][lr]=b1.x; Bs[lc+5][lr]=b1.y; Bs[lc+6][lr]=b1.z; Bs[lc+7][lr]=b1.w;
    __syncthreads();
#pragma unroll
    for (int k = 0; k < 32; ++k) {
      float4 aq = *(const float4*)&As[k][ty*4];
      float4 bq = *(const float4*)&Bs[k][tx*4];
      float a[4] = {aq.x, aq.y, aq.z, aq.w};
      float bb[4] = {bq.x, bq.y, bq.z, bq.w};
#pragma unroll
      for (int r = 0; r < 4; ++r)
#pragma unroll
        for (int c = 0; c < 4; ++c) acc[r][c] += a[r]*bb[c];
    }
  }
#pragma unroll
  for (int r = 0; r < 4; ++r) {
    float4 v = make_float4(acc[r][0], acc[r][1], acc[r][2], acc[r][3]);
    *(float4*)(H2 + (size_t)(i0 + ty*4 + r) * NQKV_ + j0 + tx*4) = v;
  }
}

// ---------------------------------------------------------------------------
// K1b: repack Kn -> bf16 [b][h][j][32]   (524288 elems)
// ---------------------------------------------------------------------------
__global__ __launch_bounds__(256) void k1b_repack(const float* __restrict__ H2,
                                                  unsigned short* __restrict__ Knb) {
  int e = blockIdx.x * 256 + threadIdx.x;
  int bh = e >> 14, rem = e & 16383;
  int j = rem >> 5, k = rem & 31;
  int b = bh >> 3, h = bh & 7;
  Knb[e] = f2bf(H2[((size_t)b * S_ + j) * NQKV_ + h * TOT_ + KS_ + k]);
}

// ---------------------------------------------------------------------------
// K3 fused: per (b,i): scores = scale*(Qn.Kn + qrr.rd) + mask ; softmax ;
//   probs (bf16) -> global ; pr = p.rd ; route-ctx -> ctx
// ---------------------------------------------------------------------------
__global__ __launch_bounds__(256) void k3_fused(const float* __restrict__ rd,
                                                const float* __restrict__ H2,
                                                const unsigned short* __restrict__ Knb,
                                                const float* __restrict__ Wd,
                                                const float* __restrict__ Wroute,
                                                const float* __restrict__ mask,
                                                unsigned short* __restrict__ probs,
                                                float* __restrict__ ctx) {
  __shared__ unsigned int rdru[512][9];   // route row, packed bf16 pairs
  __shared__ float sc[8][513];
  __shared__ float qlds[8][32];
  __shared__ float qrr[8][16];
  __shared__ float prp[4][64][2];
  __shared__ float prf[8][16];
  const int t = threadIdx.x;
  const int row = blockIdx.x;        // b*512 + i
  const int b = row >> 9;
  const int i = row & 511;

  // Qn row to LDS
  {
    int h = t >> 5, k = t & 31;
    qlds[h][k] = H2[(size_t)row * NQKV_ + h * TOT_ + k];
  }
  // qrr[h][r] = sum_k Qr[h][k] * Wd[h*8+k][r]
  if (t < 128) {
    int h = t >> 4, r = t & 15;
    float s = 0.f;
#pragma unroll
    for (int k = 0; k < 8; ++k)
      s += H2[(size_t)row * NQKV_ + h * TOT_ + 96 + k] * Wd[(h*8 + k) * 16 + r];
    qrr[h][r] = s;
  }
  // stage route row (512 x 16) as packed bf16
  const float4* rp = (const float4*)(rd + (size_t)row * 512 * 16);
#pragma unroll
  for (int q = 0; q < 8; ++q) {
    int idx = q * 256 + t;
    float4 v = rp[idx];
    int j = idx >> 2, ru = (idx & 3) * 2;
    rdru[j][ru]   = (unsigned int)f2bf(v.x) | ((unsigned int)f2bf(v.y) << 16);
    rdru[j][ru+1] = (unsigned int)f2bf(v.z) | ((unsigned int)f2bf(v.w) << 16);
  }
  __syncthreads();

  // pass A: scores (inline QK from bf16 K + route term)
  const float scal = 0.15811388300841898f;   // 1/sqrt(40)
#pragma unroll 1
  for (int h = 0; h < 8; ++h) {
    float qf[32];
#pragma unroll
    for (int k4i = 0; k4i < 8; ++k4i) {
      float4 q4 = *(const float4*)&qlds[h][k4i*4];
      qf[k4i*4+0]=q4.x; qf[k4i*4+1]=q4.y; qf[k4i*4+2]=q4.z; qf[k4i*4+3]=q4.w;
    }
#pragma unroll
    for (int half = 0; half < 2; ++half) {
      int j = half * 256 + t;
      const uint4* kp4 = (const uint4*)(Knb + (((size_t)(b*8 + h)) * S_ + j) * 32);
      uint4 u0 = kp4[0], u1 = kp4[1], u2 = kp4[2], u3 = kp4[3];
      float s = qk8(qf, u0) + qk8(qf+8, u1) + qk8(qf+16, u2) + qk8(qf+24, u3);
      float s2 = 0.f;
#pragma unroll
      for (int ru = 0; ru < 8; ++ru) {
        unsigned int u = rdru[j][ru];
        s2 += qrr[h][2*ru] * bfu2f(u & 0xffffu) + qrr[h][2*ru+1] * bfu2f(u >> 16);
      }
      sc[h][j] = scal * (s + s2) + mask[b * S_ + j];
    }
  }
  __syncthreads();

  // softmax per head (one wave -> 2 heads); write p to sc and bf16 probs
  const int wave = t >> 6, lane = t & 63;
  for (int hh = 0; hh < 2; ++hh) {
    int h = wave * 2 + hh;
    float vals[8];
    float m = -1e30f;
#pragma unroll
    for (int c = 0; c < 8; ++c) { vals[c] = sc[h][lane + 64*c]; m = fmaxf(m, vals[c]); }
#pragma unroll
    for (int o = 32; o; o >>= 1) m = fmaxf(m, __shfl_xor(m, o));
    float ssum = 0.f;
#pragma unroll
    for (int c = 0; c < 8; ++c) { vals[c] = __expf(vals[c] - m); ssum += vals[c]; }
#pragma unroll
    for (int o = 32; o; o >>= 1) ssum += __shfl_xor(ssum, o);
    float inv = 1.0f / ssum;
    unsigned short* pout = probs + (((size_t)(b*8 + h)) * S_ + i) * S_;
#pragma unroll
    for (int c = 0; c < 8; ++c) {
      int j = lane + 64*c;
      float p = vals[c] * inv;
      sc[h][j] = p;
      pout[j] = f2bf(p);
    }
  }
  __syncthreads();

  // pass B: pr[h][r] = sum_j p[h][j] * rd[j][r]
  {
    int c = t & 63, qj = t >> 6;
    int h = c >> 3, ru = c & 7;
    float p0 = 0.f, p1 = 0.f;
    int j0 = qj * 128;
    for (int jj = 0; jj < 128; ++jj) {
      int j = j0 + jj;
      unsigned int u = rdru[j][ru];
      float p = sc[h][j];
      p0 += p * bfu2f(u & 0xffffu);
      p1 += p * bfu2f(u >> 16);
    }
    prp[qj][c][0] = p0; prp[qj][c][1] = p1;
  }
  __syncthreads();
  if (t < 128) {
    int h = t >> 4, r = t & 15;
    int c = h * 8 + (r >> 1), part = r & 1;
    prf[h][r] = prp[0][c][part] + prp[1][c][part] + prp[2][c][part] + prp[3][c][part];
  }
  __syncthreads();

  // route context
  {
    int h = t >> 5;
    float s = 0.f;
#pragma unroll
    for (int r = 0; r < 16; ++r) s += prf[h][r] * Wroute[t * 16 + r];
    ctx[(size_t)row * 256 + t] = s;
  }
}

// ---------------------------------------------------------------------------
// K4: ctx[b, i, h*32+v] += sum_j probs[b,h,i,j] * V[b,h,j,v]   (j-split x2)
// ---------------------------------------------------------------------------
__global__ __launch_bounds__(256) void k4_pv(const unsigned short* __restrict__ probs,
                                             const float* __restrict__ H2,
                                             float* __restrict__ ctx) {
  __shared__ float Pt[64][65];
  __shared__ float Vt[64][33];
  const int t = threadIdx.x;
  const int bz = blockIdx.y;           // b*8+h
  const int b = bz >> 3, h = bz & 7;
  const int i0 = blockIdx.x * 64;
  const int jh = blockIdx.z;
  const int v = t & 31, ig = t >> 5;
  const float* Vbase = H2 + (size_t)b * S_ * NQKV_ + h * TOT_ + 2*KS_;
  const int pr_ = t >> 2, pc = (t & 3) * 16;
  const int vr = t >> 2, vc = (t & 3) * 8;
  float acc[8] = {};

  for (int jt = jh*4; jt < jh*4 + 4; ++jt) {
    const unsigned short* pb = probs + (((size_t)bz * S_) + i0 + pr_) * S_ + jt*64 + pc;
    uint4 pa = *(const uint4*)pb;
    uint4 pc4 = *(const uint4*)(pb + 8);
    float4 v0 = *(const float4*)(Vbase + (size_t)(jt*64 + vr) * NQKV_ + vc);
    float4 v1 = *(const float4*)(Vbase + (size_t)(jt*64 + vr) * NQKV_ + vc + 4);
    __syncthreads();
    Pt[pr_][pc+0]  = bfu2f(pa.x & 0xffffu);  Pt[pr_][pc+1]  = bfu2f(pa.x >> 16);
    Pt[pr_][pc+2]  = bfu2f(pa.y & 0xffffu);  Pt[pr_][pc+3]  = bfu2f(pa.y >> 16);
    Pt[pr_][pc+4]  = bfu2f(pa.z & 0xffffu);  Pt[pr_][pc+5]  = bfu2f(pa.z >> 16);
    Pt[pr_][pc+6]  = bfu2f(pa.w & 0xffffu);  Pt[pr_][pc+7]  = bfu2f(pa.w >> 16);
    Pt[pr_][pc+8]  = bfu2f(pc4.x & 0xffffu); Pt[pr_][pc+9]  = bfu2f(pc4.x >> 16);
    Pt[pr_][pc+10] = bfu2f(pc4.y & 0xffffu); Pt[pr_][pc+11] = bfu2f(pc4.y >> 16);
    Pt[pr_][pc+12] = bfu2f(pc4.z & 0xffffu); Pt[pr_][pc+13] = bfu2f(pc4.z >> 16);
    Pt[pr_][pc+14] = bfu2f(pc4.w & 0xffffu); Pt[pr_][pc+15] = bfu2f(pc4.w >> 16);
    Vt[vr][vc+0]=v0.x; Vt[vr][vc+1]=v0.y; Vt[vr][vc+2]=v0.z; Vt[vr][vc+3]=v0.w;
    Vt[vr][vc+4]=v1.x; Vt[vr][vc+5]=v1.y; Vt[vr][vc+6]=v1.z; Vt[vr][vc+7]=v1.w;
    __syncthreads();
#pragma unroll
    for (int j = 0; j < 64; ++j) {
      float vv = Vt[j][v];
#pragma unroll
      for (int r = 0; r < 8; ++r) acc[r] += Pt[r*8 + ig][j] * vv;
    }
  }
#pragma unroll
  for (int r = 0; r < 8; ++r) {
    size_t addr = ((size_t)b * S_ + i0 + r*8 + ig) * 256 + h*32 + v;
    atomicAdd(&ctx[addr], acc[r]);
  }
}

// ---------------------------------------------------------------------------
// K5: out = LN(ctx @ W_out.T + b_out) + H     (8 rows per block)
// ---------------------------------------------------------------------------
__global__ __launch_bounds__(256) void k5_out(const float* __restrict__ ctx,
                                              const float* __restrict__ Wout,
                                              const float* __restrict__ bout,
                                              const float* __restrict__ lnw,
                                              const float* __restrict__ lnb,
                                              const float* __restrict__ Hin,
                                              float* __restrict__ out) {
  __shared__ float buf[8][257];
  __shared__ float uarr[8], rarr[8];
  const int t = threadIdx.x;
  const int R0 = blockIdx.x * 8;
  {
    int sr = t >> 5, c0 = (t & 31) * 8;
    const float4* cp = (const float4*)(ctx + (size_t)(R0 + sr) * 256 + c0);
    float4 a = cp[0], bq = cp[1];
    buf[sr][c0+0]=a.x;  buf[sr][c0+1]=a.y;  buf[sr][c0+2]=a.z;  buf[sr][c0+3]=a.w;
    buf[sr][c0+4]=bq.x; buf[sr][c0+5]=bq.y; buf[sr][c0+6]=bq.z; buf[sr][c0+7]=bq.w;
  }
  __syncthreads();

  float o[8];
  {
    float bo = bout[t];
#pragma unroll
    for (int r = 0; r < 8; ++r) o[r] = bo;
  }
  const float4* wp = (const float4*)(Wout + (size_t)t * 256);
  for (int d4 = 0; d4 < 64; ++d4) {
    float4 w = wp[d4];
    int d = d4 * 4;
#pragma unroll
    for (int r = 0; r < 8; ++r)
      o[r] += buf[r][d]*w.x + buf[r][d+1]*w.y + buf[r][d+2]*w.z + buf[r][d+3]*w.w;
  }
  __syncthreads();
#pragma unroll
  for (int r = 0; r < 8; ++r) buf[r][t] = o[r];
  __syncthreads();
  {
    int wave = t >> 6, lane = t & 63;
#pragma unroll
    for (int rr = 0; rr < 2; ++rr) {
      int r = wave * 2 + rr;
      float s = 0.f, sq = 0.f;
#pragma unroll
      for (int c = 0; c < 4; ++c) {
        float x = buf[r][lane + 64*c];
        s += x; sq += x*x;
      }
#pragma unroll
      for (int off = 32; off; off >>= 1) {
        s += __shfl_xor(s, off);
        sq += __shfl_xor(sq, off);
      }
      if (lane == 0) {
        float u = s * (1.0f/256.0f);
        uarr[r] = u;
        rarr[r] = rsqrtf(sq * (1.0f/256.0f) - u*u + 1e-12f);
      }
    }
  }
  __syncthreads();
  {
    float lw = lnw[t], lb = lnb[t];
#pragma unroll
    for (int r = 0; r < 8; ++r) {
      size_t R = R0 + r;
      out[R * 256 + t] = lw * (o[r] - uarr[r]) * rarr[r] + lb + Hin[R * 256 + t];
    }
  }
}

// ---------------------------------------------------------------------------
extern "C" void kernel_launch(void* const* d_in, const int* in_sizes, int n_in,
                              void* d_out, int out_size, void* d_ws, size_t ws_size,
                              hipStream_t stream) {
  const float* Hin    = (const float*)d_in[0];
  const float* rd     = (const float*)d_in[1];
  const float* mask   = (const float*)d_in[2];
  const float* Wqkv   = (const float*)d_in[3];
  const float* Wd     = (const float*)d_in[4];
  const float* Wroute = (const float*)d_in[5];
  const float* Wout   = (const float*)d_in[6];
  const float* bout   = (const float*)d_in[7];
  const float* lnw    = (const float*)d_in[8];
  const float* lnb    = (const float*)d_in[9];
  float* out = (float*)d_out;

  float* H2            = (float*)d_ws;                       // 1,703,936 f
  unsigned short* probs = (unsigned short*)(H2 + (size_t)ROWS_ * NQKV_);  // 8,388,608 us
  unsigned short* Knb   = probs + (size_t)B_ * NH_ * S_ * S_;             // 524,288 us
  float* ctx            = (float*)(Knb + (size_t)B_ * NH_ * S_ * KS_);    // 524,288 f

  k1_qkv    <<<dim3(13, 32),   256, 0, stream>>>(Hin, Wqkv, H2);
  k1b_repack<<<2048,           256, 0, stream>>>(H2, Knb);
  k3_fused  <<<2048,           256, 0, stream>>>(rd, H2, Knb, Wd, Wroute, mask, probs, ctx);
  k4_pv     <<<dim3(8, 32, 2), 256, 0, stream>>>(probs, H2, ctx);
  k5_out    <<<256,            256, 0, stream>>>(ctx, Wout, bout, lnw, lnb, Hin, out);
}

// Round 4
// 196.373 us; speedup vs baseline: 1.4124x; 1.3437x over previous
//
#include <hip/hip_runtime.h>
#include <cmath>

#define B_    4
#define S_    512
#define NH_   8
#define TOT_  104
#define NQKV_ 832
#define ROWS_ 2048

typedef float f32x4 __attribute__((ext_vector_type(4)));
typedef short short8 __attribute__((ext_vector_type(8)));

__device__ inline float bfu2f(unsigned int bits16) {
  union { unsigned int i; float f; } v; v.i = bits16 << 16; return v.f;
}
__device__ inline unsigned short f2bf(float f) {
  union { float f; unsigned int i; } v; v.f = f;
  unsigned int r = v.i + 0x7fffu + ((v.i >> 16) & 1u);
  return (unsigned short)(r >> 16);
}
__device__ inline short8 ld8(const unsigned short* p) {
  union { uint4 u; short8 s; } v; v.u = *(const uint4*)p; return v.s;
}

// ---------------------------------------------------------------------------
// cast f32 -> bf16, 4 elems/thread (grid sized exactly)
// ---------------------------------------------------------------------------
__global__ __launch_bounds__(256) void castf2bf(const float* __restrict__ in,
                                                unsigned short* __restrict__ outp) {
  int idx = blockIdx.x * 256 + threadIdx.x;
  float4 v = ((const float4*)in)[idx];
  uint2 u;
  u.x = (unsigned int)f2bf(v.x) | ((unsigned int)f2bf(v.y) << 16);
  u.y = (unsigned int)f2bf(v.z) | ((unsigned int)f2bf(v.w) << 16);
  ((uint2*)outp)[idx] = u;
}

// ---------------------------------------------------------------------------
// K1: MFMA QKV projection. C[2048,832] = Hbf @ Wqb^T. Epilogue scatters to
// Qnb/Knb [bh][i][32] bf16, Vtb [bh][v][512] bf16 (transposed), Qr f32.
// ---------------------------------------------------------------------------
__global__ __launch_bounds__(256) void k1_qkv(const unsigned short* __restrict__ Hbf,
                                              const unsigned short* __restrict__ Wqb,
                                              unsigned short* __restrict__ Qnb,
                                              unsigned short* __restrict__ Knb,
                                              unsigned short* __restrict__ Vtb,
                                              float* __restrict__ Qr) {
  const int t = threadIdx.x;
  const int w = t >> 6, l = t & 63;
  const int lm = l & 15, lk = (l >> 4) << 3;
  const int i0 = blockIdx.y * 64 + w * 16;
  const int n0 = blockIdx.x * 64;
  f32x4 acc[4] = {};
  for (int k0 = 0; k0 < 256; k0 += 32) {
    short8 a = ld8(Hbf + (size_t)(i0 + lm) * 256 + k0 + lk);
#pragma unroll
    for (int nf = 0; nf < 4; ++nf) {
      short8 b = ld8(Wqb + (size_t)(n0 + nf * 16 + lm) * 256 + k0 + lk);
      acc[nf] = __builtin_amdgcn_mfma_f32_16x16x32_bf16(a, b, acc[nf], 0, 0, 0);
    }
  }
  const int rbase = i0 + ((l >> 4) << 2);
#pragma unroll
  for (int nf = 0; nf < 4; ++nf) {
#pragma unroll
    for (int r = 0; r < 4; ++r) {
      int row = rbase + r;
      int c = n0 + nf * 16 + lm;
      int b_ = row >> 9, i = row & 511;
      int h = c / 104, o = c - h * 104;
      float v = acc[nf][r];
      size_t bh = (size_t)(b_ * 8 + h);
      if (o < 32)       Qnb[(bh * 512 + i) * 32 + o] = f2bf(v);
      else if (o < 64)  Knb[(bh * 512 + i) * 32 + (o - 32)] = f2bf(v);
      else if (o < 96)  Vtb[(bh * 32 + (o - 64)) * 512 + i] = f2bf(v);
      else              Qr[(size_t)row * 64 + h * 8 + (o - 96)] = v;
    }
  }
}

// ---------------------------------------------------------------------------
// K1c: qrr[row][h*16+r] = sum_k Qr[row][h*8+k] * Wd[(h*8+k)*16+r]
// ---------------------------------------------------------------------------
__global__ __launch_bounds__(256) void k1c_qrr(const float* __restrict__ Qr,
                                               const float* __restrict__ Wd,
                                               float* __restrict__ qrrg) {
  int t = threadIdx.x;
  int row = blockIdx.x * 2 + (t >> 7);
  int c = t & 127, h = c >> 4, r = c & 15;
  float s = 0.f;
#pragma unroll
  for (int k = 0; k < 8; ++k)
    s += Qr[(size_t)row * 64 + h * 8 + k] * Wd[(h * 8 + k) * 16 + r];
  qrrg[(size_t)row * 128 + c] = s;
}

// ---------------------------------------------------------------------------
// K2: MFMA QK^T per (b,h): sqk[bh][i][j] bf16 = Qn[512,32] @ Kn[512,32]^T
// ---------------------------------------------------------------------------
__global__ __launch_bounds__(256) void k2_qk(const unsigned short* __restrict__ Qnb,
                                             const unsigned short* __restrict__ Knb,
                                             unsigned short* __restrict__ sqk) {
  const int t = threadIdx.x;
  const int w = t >> 6, l = t & 63;
  const int lm = l & 15, lk = (l >> 4) << 3;
  const int bh = blockIdx.z;
  const int i0 = blockIdx.y * 64 + w * 16, j0 = blockIdx.x * 64;
  short8 a = ld8(Qnb + ((size_t)bh * 512 + i0 + lm) * 32 + lk);
  f32x4 acc[4] = {};
#pragma unroll
  for (int nf = 0; nf < 4; ++nf) {
    short8 b = ld8(Knb + ((size_t)bh * 512 + j0 + nf * 16 + lm) * 32 + lk);
    acc[nf] = __builtin_amdgcn_mfma_f32_16x16x32_bf16(a, b, acc[nf], 0, 0, 0);
  }
  const int rbase = i0 + ((l >> 4) << 2);
#pragma unroll
  for (int nf = 0; nf < 4; ++nf)
#pragma unroll
    for (int r = 0; r < 4; ++r)
      sqk[((size_t)bh * 512 + rbase + r) * 512 + j0 + nf * 16 + lm] = f2bf(acc[nf][r]);
}

// ---------------------------------------------------------------------------
// K3: per (b,i): scores = scale*(sqk + qrr.rd) + mask ; softmax ;
//     probs bf16 -> global ; pr = p.rd ; route-ctx -> ctx
// ---------------------------------------------------------------------------
__global__ __launch_bounds__(256) void k3_route(const float* __restrict__ rd,
                                                const unsigned short* __restrict__ sqk,
                                                const float* __restrict__ qrrg,
                                                const float* __restrict__ Wroute,
                                                const float* __restrict__ mask,
                                                unsigned short* __restrict__ probs,
                                                float* __restrict__ ctx) {
  __shared__ float rdf[512][17];
  __shared__ unsigned int sc_bf[8][257];   // packed (j, j+256) bf16 pairs
  __shared__ float qrr[8][16];
  __shared__ float prp[4][64][2];
  __shared__ float prf[8][16];
  const int t = threadIdx.x;
  const int row = blockIdx.x, b = row >> 9, i = row & 511;

  // stage rd row (512 x 16 f32)
  const float4* rp = (const float4*)(rd + (size_t)row * 8192);
#pragma unroll
  for (int q = 0; q < 8; ++q) {
    int idx = q * 256 + t;
    float4 v = rp[idx];
    int j = idx >> 2, c0 = (idx & 3) * 4;
    rdf[j][c0] = v.x; rdf[j][c0 + 1] = v.y; rdf[j][c0 + 2] = v.z; rdf[j][c0 + 3] = v.w;
  }
  if (t < 128) ((float*)qrr)[t] = qrrg[(size_t)row * 128 + t];
  __syncthreads();

  // pass A: thread owns j = t (lo) and j+256 (hi)
  const float scal = 0.15811388300841898f;
  {
    float rlo[16], rhi[16];
#pragma unroll
    for (int q = 0; q < 4; ++q) {
      float4 a = *(const float4*)&rdf[t][q * 4];
      float4 c = *(const float4*)&rdf[t + 256][q * 4];
      rlo[q*4]=a.x; rlo[q*4+1]=a.y; rlo[q*4+2]=a.z; rlo[q*4+3]=a.w;
      rhi[q*4]=c.x; rhi[q*4+1]=c.y; rhi[q*4+2]=c.z; rhi[q*4+3]=c.w;
    }
    float mlo = mask[b * 512 + t], mhi = mask[b * 512 + t + 256];
#pragma unroll
    for (int h = 0; h < 8; ++h) {
      float slo = 0.f, shi = 0.f;
#pragma unroll
      for (int r = 0; r < 16; ++r) { slo += qrr[h][r] * rlo[r]; shi += qrr[h][r] * rhi[r]; }
      const unsigned short* qp = sqk + ((size_t)(b * 8 + h) * 512 + i) * 512;
      float qlo = bfu2f(qp[t]), qhi = bfu2f(qp[t + 256]);
      float vlo = scal * (qlo + slo) + mlo;
      float vhi = scal * (qhi + shi) + mhi;
      sc_bf[h][t] = (unsigned int)f2bf(vlo) | ((unsigned int)f2bf(vhi) << 16);
    }
  }
  __syncthreads();

  // softmax: wave handles 2 heads; lane covers jj = lane + 64*cq, both halves
  const int wave = t >> 6, lane = t & 63;
  for (int hh = 0; hh < 2; ++hh) {
    int h = wave * 2 + hh;
    float vlo[4], vhi[4];
    float m = -1e30f;
#pragma unroll
    for (int cq = 0; cq < 4; ++cq) {
      unsigned int u = sc_bf[h][lane + 64 * cq];
      vlo[cq] = bfu2f(u & 0xffffu); vhi[cq] = bfu2f(u >> 16);
      m = fmaxf(m, fmaxf(vlo[cq], vhi[cq]));
    }
#pragma unroll
    for (int o = 32; o; o >>= 1) m = fmaxf(m, __shfl_xor(m, o));
    float ssum = 0.f;
#pragma unroll
    for (int cq = 0; cq < 4; ++cq) {
      vlo[cq] = __expf(vlo[cq] - m); vhi[cq] = __expf(vhi[cq] - m);
      ssum += vlo[cq] + vhi[cq];
    }
#pragma unroll
    for (int o = 32; o; o >>= 1) ssum += __shfl_xor(ssum, o);
    float inv = 1.0f / ssum;
    unsigned short* pout = probs + ((size_t)(b * 8 + h) * 512 + i) * 512;
#pragma unroll
    for (int cq = 0; cq < 4; ++cq) {
      int jj = lane + 64 * cq;
      unsigned short plo = f2bf(vlo[cq] * inv), phi = f2bf(vhi[cq] * inv);
      pout[jj] = plo; pout[jj + 256] = phi;
      sc_bf[h][jj] = (unsigned int)plo | ((unsigned int)phi << 16);
    }
  }
  __syncthreads();

  // pass B: pr[h][r] = sum_j p[h][j]*rd[j][r]
  {
    int c = t & 63, qj = t >> 6;
    int h = c >> 3, ru = c & 7;
    float p0 = 0.f, p1 = 0.f;
    for (int jj = qj * 64; jj < qj * 64 + 64; ++jj) {
      unsigned int u = sc_bf[h][jj];
      float plo = bfu2f(u & 0xffffu), phi = bfu2f(u >> 16);
      p0 += plo * rdf[jj][2 * ru]     + phi * rdf[jj + 256][2 * ru];
      p1 += plo * rdf[jj][2 * ru + 1] + phi * rdf[jj + 256][2 * ru + 1];
    }
    prp[qj][c][0] = p0; prp[qj][c][1] = p1;
  }
  __syncthreads();
  if (t < 128) {
    int h = t >> 4, r = t & 15;
    int c = h * 8 + (r >> 1), part = r & 1;
    prf[h][r] = prp[0][c][part] + prp[1][c][part] + prp[2][c][part] + prp[3][c][part];
  }
  __syncthreads();

  // route context
  {
    int h = t >> 5;
    float s = 0.f;
#pragma unroll
    for (int r = 0; r < 16; ++r) s += prf[h][r] * Wroute[t * 16 + r];
    ctx[(size_t)row * 256 + t] = s;
  }
}

// ---------------------------------------------------------------------------
// K4: MFMA PV per (b,h, i-tile 64): ctx[b*512+i][h*32+v] += P @ V
// ---------------------------------------------------------------------------
__global__ __launch_bounds__(256) void k4_pv(const unsigned short* __restrict__ probs,
                                             const unsigned short* __restrict__ Vtb,
                                             float* __restrict__ ctx) {
  const int t = threadIdx.x;
  const int w = t >> 6, l = t & 63;
  const int lm = l & 15, lk = (l >> 4) << 3;
  const int bh = blockIdx.y;
  const int b = bh >> 3, h = bh & 7;
  const int irow = blockIdx.x * 64 + w * 16 + lm;
  f32x4 acc[2] = {};
  for (int k0 = 0; k0 < 512; k0 += 32) {
    short8 a = ld8(probs + ((size_t)bh * 512 + irow) * 512 + k0 + lk);
#pragma unroll
    for (int nf = 0; nf < 2; ++nf) {
      short8 bb = ld8(Vtb + ((size_t)bh * 32 + nf * 16 + lm) * 512 + k0 + lk);
      acc[nf] = __builtin_amdgcn_mfma_f32_16x16x32_bf16(a, bb, acc[nf], 0, 0, 0);
    }
  }
  const int rbase = blockIdx.x * 64 + w * 16 + ((l >> 4) << 2);
#pragma unroll
  for (int nf = 0; nf < 2; ++nf)
#pragma unroll
    for (int r = 0; r < 4; ++r) {
      size_t addr = ((size_t)b * 512 + rbase + r) * 256 + h * 32 + nf * 16 + lm;
      ctx[addr] += acc[nf][r];
    }
}

// ---------------------------------------------------------------------------
// K5: out = LN(ctx @ W_out.T + b_out) + H   (8 rows/block, f32)
// ---------------------------------------------------------------------------
__global__ __launch_bounds__(256) void k5_out(const float* __restrict__ ctx,
                                              const float* __restrict__ Wout,
                                              const float* __restrict__ bout,
                                              const float* __restrict__ lnw,
                                              const float* __restrict__ lnb,
                                              const float* __restrict__ Hin,
                                              float* __restrict__ out) {
  __shared__ float buf[8][257];
  __shared__ float uarr[8], rarr[8];
  const int t = threadIdx.x;
  const int R0 = blockIdx.x * 8;
  {
    int sr = t >> 5, c0 = (t & 31) * 8;
    const float4* cp = (const float4*)(ctx + (size_t)(R0 + sr) * 256 + c0);
    float4 a = cp[0], bq = cp[1];
    buf[sr][c0+0]=a.x;  buf[sr][c0+1]=a.y;  buf[sr][c0+2]=a.z;  buf[sr][c0+3]=a.w;
    buf[sr][c0+4]=bq.x; buf[sr][c0+5]=bq.y; buf[sr][c0+6]=bq.z; buf[sr][c0+7]=bq.w;
  }
  __syncthreads();

  float o[8];
  {
    float bo = bout[t];
#pragma unroll
    for (int r = 0; r < 8; ++r) o[r] = bo;
  }
  const float4* wp = (const float4*)(Wout + (size_t)t * 256);
  for (int d4 = 0; d4 < 64; ++d4) {
    float4 w = wp[d4];
    int d = d4 * 4;
#pragma unroll
    for (int r = 0; r < 8; ++r)
      o[r] += buf[r][d]*w.x + buf[r][d+1]*w.y + buf[r][d+2]*w.z + buf[r][d+3]*w.w;
  }
  __syncthreads();
#pragma unroll
  for (int r = 0; r < 8; ++r) buf[r][t] = o[r];
  __syncthreads();
  {
    int wave = t >> 6, lane = t & 63;
#pragma unroll
    for (int rr = 0; rr < 2; ++rr) {
      int r = wave * 2 + rr;
      float s = 0.f, sq = 0.f;
#pragma unroll
      for (int c = 0; c < 4; ++c) {
        float x = buf[r][lane + 64*c];
        s += x; sq += x*x;
      }
#pragma unroll
      for (int off = 32; off; off >>= 1) {
        s += __shfl_xor(s, off);
        sq += __shfl_xor(sq, off);
      }
      if (lane == 0) {
        float u = s * (1.0f/256.0f);
        uarr[r] = u;
        rarr[r] = rsqrtf(sq * (1.0f/256.0f) - u*u + 1e-12f);
      }
    }
  }
  __syncthreads();
  {
    float lw = lnw[t], lb = lnb[t];
#pragma unroll
    for (int r = 0; r < 8; ++r) {
      size_t R = R0 + r;
      out[R * 256 + t] = lw * (o[r] - uarr[r]) * rarr[r] + lb + Hin[R * 256 + t];
    }
  }
}

// ---------------------------------------------------------------------------
extern "C" void kernel_launch(void* const* d_in, const int* in_sizes, int n_in,
                              void* d_out, int out_size, void* d_ws, size_t ws_size,
                              hipStream_t stream) {
  const float* Hin    = (const float*)d_in[0];
  const float* rd     = (const float*)d_in[1];
  const float* mask   = (const float*)d_in[2];
  const float* Wqkv   = (const float*)d_in[3];
  const float* Wd     = (const float*)d_in[4];
  const float* Wroute = (const float*)d_in[5];
  const float* Wout   = (const float*)d_in[6];
  const float* bout   = (const float*)d_in[7];
  const float* lnw    = (const float*)d_in[8];
  const float* lnb    = (const float*)d_in[9];
  float* out = (float*)d_out;

  unsigned short* Hbf   = (unsigned short*)d_ws;       // 524,288
  unsigned short* Wqb   = Hbf + 524288;                // 212,992
  unsigned short* Qnb   = Wqb + 212992;                // 524,288
  unsigned short* Knb   = Qnb + 524288;                // 524,288
  unsigned short* Vtb   = Knb + 524288;                // 524,288
  unsigned short* sqk   = Vtb + 524288;                // 8,388,608
  unsigned short* probs = sqk + 8388608;               // 8,388,608
  float* Qr   = (float*)(probs + 8388608);             // 131,072 f
  float* qrrg = Qr + 131072;                           // 262,144 f
  float* ctx  = qrrg + 262144;                         // 524,288 f
  // total = 41,844,736 B (fits: R1 layout proved >= 42.4 MB available)

  castf2bf<<<512,            256, 0, stream>>>(Hin, Hbf);
  castf2bf<<<208,            256, 0, stream>>>(Wqkv, Wqb);
  k1_qkv  <<<dim3(13, 32),   256, 0, stream>>>(Hbf, Wqb, Qnb, Knb, Vtb, Qr);
  k1c_qrr <<<1024,           256, 0, stream>>>(Qr, Wd, qrrg);
  k2_qk   <<<dim3(8, 8, 32), 256, 0, stream>>>(Qnb, Knb, sqk);
  k3_route<<<2048,           256, 0, stream>>>(rd, sqk, qrrg, Wroute, mask, probs, ctx);
  k4_pv   <<<dim3(8, 32),    256, 0, stream>>>(probs, Vtb, ctx);
  k5_out  <<<256,            256, 0, stream>>>(ctx, Wout, bout, lnw, lnb, Hin, out);
}